// Round 3
// baseline (133.832 us; speedup 1.0000x reference)
//
#include <hip/hip_runtime.h>
#include <hip/hip_bf16.h>

#define B_    2
#define SQ_   2048
#define SK_   2048
#define NH_   16
#define DH_   64
#define WIN_  256
#define NEG_  -30000.0f

typedef __bf16 bf16_t;
typedef bf16_t bf16x8 __attribute__((ext_vector_type(8)));
typedef bf16_t bf16x4 __attribute__((ext_vector_type(4)));
typedef float  f32x4  __attribute__((ext_vector_type(4)));

// sK rows are 64 d-elements -> stride 72 (144 B, 16B-aligned, 2-way bank alias = free)
// sVT/sP rows are 32 key-elements -> stride 40 (80 B, 16B-aligned)
#define KSTRIDE 72
#define VSTRIDE 40
#define PSTRIDE 40

__global__ __launch_bounds__(256, 2)
void fa_fwd(const float* __restrict__ qg, const float* __restrict__ kvg,
            float* __restrict__ outg) {
  const int tid  = threadIdx.x;
  const int wid  = tid >> 6;
  const int lane = tid & 63;
  const int quad = lane >> 4;
  const int li   = lane & 15;

  const int bid = blockIdx.x;
  const int qb  = bid & 31;   // 32 q-blocks of 64 rows
  const int bh  = bid >> 5;   // 0..31
  const int b   = bh >> 4;
  const int h   = bh & 15;

  const int q0b = qb * 64;
  const int q0  = q0b + wid * 16;   // this wave's 16 query rows

  __shared__ __align__(16) bf16_t sK [32 * KSTRIDE];      // K tile [key][d0..63]
  __shared__ __align__(16) bf16_t sVT[64 * VSTRIDE];      // V tile transposed [d][key0..31]
  __shared__ __align__(16) bf16_t sP [4 * 16 * PSTRIDE];  // per-wave P [q][key0..31]
  bf16_t* pl = sP + wid * 16 * PSTRIDE;

  // ---- load Q fragments, fold attn scale * log2(e) so softmax uses exp2 ----
  const float qscale = 0.125f * 1.44269504088896340736f;
  const float* qrow = qg + ((size_t)((b * SQ_ + q0 + li) * NH_ + h)) * DH_;
  bf16x8 qfrag[2];
#pragma unroll
  for (int c = 0; c < 2; ++c) {
    f32x4 a0 = *(const f32x4*)(qrow + c * 32 + quad * 8);
    f32x4 a1 = *(const f32x4*)(qrow + c * 32 + quad * 8 + 4);
#pragma unroll
    for (int i = 0; i < 4; ++i) {
      qfrag[c][i]     = (bf16_t)(a0[i] * qscale);
      qfrag[c][i + 4] = (bf16_t)(a1[i] * qscale);
    }
  }

  f32x4 oacc[4];
#pragma unroll
  for (int t = 0; t < 4; ++t) { f32x4 z = {0.f, 0.f, 0.f, 0.f}; oacc[t] = z; }
  float m = NEG_, l = 0.f;

  // block-uniform key range, 32-aligned
  int klo = q0b - WIN_; if (klo < 0) klo = 0; klo &= ~31;
  int khi = q0b + 63 + WIN_ + 1; if (khi > SK_) khi = SK_; khi = (khi + 31) & ~31;

  const float* kbase = kvg + (size_t)b * SK_ * 2 * NH_ * DH_ + (size_t)h * DH_;
  const float* vbase = kbase + NH_ * DH_;
  const size_t krow_stride = 2 * NH_ * DH_;  // 2048 floats between consecutive keys

  // cooperative staging: 256 threads cover 32 keys x 64 d
  const int skey = tid >> 3;        // 0..31
  const int sd0  = (tid & 7) * 8;   // 0,8,...,56

  for (int kk = klo; kk < khi; kk += 32) {
    // ---- stage K tile (row-major) + V tile (transposed) ----
    {
      const float* kr = kbase + (size_t)(kk + skey) * krow_stride + sd0;
      f32x4 a0 = *(const f32x4*)kr;
      f32x4 a1 = *(const f32x4*)(kr + 4);
      bf16x8 w;
#pragma unroll
      for (int i = 0; i < 4; ++i) { w[i] = (bf16_t)a0[i]; w[i + 4] = (bf16_t)a1[i]; }
      *(bf16x8*)(sK + skey * KSTRIDE + sd0) = w;

      const float* vr = vbase + (size_t)(kk + skey) * krow_stride + sd0;
      f32x4 b0 = *(const f32x4*)vr;
      f32x4 b1 = *(const f32x4*)(vr + 4);
#pragma unroll
      for (int i = 0; i < 4; ++i) {
        sVT[(sd0 + i)     * VSTRIDE + skey] = (bf16_t)b0[i];
        sVT[(sd0 + 4 + i) * VSTRIDE + skey] = (bf16_t)b1[i];
      }
    }
    __syncthreads();

    // ---- S^T = K . Q^T : two 16-key subtiles, D=64 as two K=32 chunks ----
    f32x4 sc[2];
#pragma unroll
    for (int s = 0; s < 2; ++s) {
      bf16x8 kf0 = *(const bf16x8*)(sK + (s * 16 + li) * KSTRIDE + quad * 8);
      bf16x8 kf1 = *(const bf16x8*)(sK + (s * 16 + li) * KSTRIDE + 32 + quad * 8);
      f32x4 acc = {0.f, 0.f, 0.f, 0.f};
      acc = __builtin_amdgcn_mfma_f32_16x16x32_bf16(kf0, qfrag[0], acc, 0, 0, 0);
      acc = __builtin_amdgcn_mfma_f32_16x16x32_bf16(kf1, qfrag[1], acc, 0, 0, 0);
      sc[s] = acc;
    }

    // ---- window mask (unconditional; masked groups self-heal via alpha=0) ----
    const int qa = q0 + li;
#pragma unroll
    for (int s = 0; s < 2; ++s)
#pragma unroll
      for (int r = 0; r < 4; ++r) {
        int key = kk + s * 16 + quad * 4 + r;
        unsigned dd = (unsigned)(key - qa + WIN_);
        if (dd > 2u * WIN_) sc[s][r] = NEG_;
      }

    // ---- online softmax, state per column q = li ----
    float tmax = fmaxf(fmaxf(fmaxf(sc[0][0], sc[0][1]), fmaxf(sc[0][2], sc[0][3])),
                       fmaxf(fmaxf(sc[1][0], sc[1][1]), fmaxf(sc[1][2], sc[1][3])));
    tmax = fmaxf(tmax, __shfl_xor(tmax, 16));
    tmax = fmaxf(tmax, __shfl_xor(tmax, 32));
    float mnew  = fmaxf(m, tmax);
    float alpha = exp2f(m - mnew);
    float psum = 0.f;
    bf16x4 pk[2];
#pragma unroll
    for (int s = 0; s < 2; ++s)
#pragma unroll
      for (int r = 0; r < 4; ++r) {
        float p = exp2f(sc[s][r] - mnew);
        psum += p;
        pk[s][r] = (bf16_t)p;
      }
    psum += __shfl_xor(psum, 16);
    psum += __shfl_xor(psum, 32);
    l = l * alpha + psum;
    m = mnew;

    // ---- write P transposed to [q][key] (4 consecutive keys -> b64 store) ----
#pragma unroll
    for (int s = 0; s < 2; ++s)
      *(bf16x4*)(pl + li * PSTRIDE + s * 16 + quad * 4) = pk[s];

    __syncthreads();   // order the cross-lane P round-trip

    // ---- rescale O accumulators (alpha per q-row = quad*4+r) ----
    float al[4];
#pragma unroll
    for (int r = 0; r < 4; ++r) al[r] = __shfl(alpha, quad * 4 + r);
#pragma unroll
    for (int t = 0; t < 4; ++t) {
      oacc[t][0] *= al[0]; oacc[t][1] *= al[1];
      oacc[t][2] *= al[2]; oacc[t][3] *= al[3];
    }

    // ---- O += P . V  (A = P rows from LDS, B = V via transposed tile) ----
    bf16x8 pf = *(const bf16x8*)(pl + li * PSTRIDE + quad * 8);
#pragma unroll
    for (int t = 0; t < 4; ++t) {
      bf16x8 vf = *(const bf16x8*)(sVT + (16 * t + li) * VSTRIDE + quad * 8);
      oacc[t] = __builtin_amdgcn_mfma_f32_16x16x32_bf16(pf, vf, oacc[t], 0, 0, 0);
    }
    __syncthreads();
  }

  // ---- epilogue: divide by l (per q-row), write O[q=quad*4+r][d=16t+li] ----
  float rl[4];
#pragma unroll
  for (int r = 0; r < 4; ++r) {
    float lv = __shfl(l, quad * 4 + r);
    rl[r] = 1.0f / lv;
  }
  float* orow = outg + ((size_t)((b * SQ_ + q0) * NH_ + h)) * DH_;
#pragma unroll
  for (int t = 0; t < 4; ++t)
#pragma unroll
    for (int r = 0; r < 4; ++r)
      orow[(size_t)(quad * 4 + r) * (NH_ * DH_) + 16 * t + li] = oacc[t][r] * rl[r];
}

extern "C" void kernel_launch(void* const* d_in, const int* in_sizes, int n_in,
                              void* d_out, int out_size, void* d_ws, size_t ws_size,
                              hipStream_t stream) {
  (void)in_sizes; (void)n_in; (void)out_size; (void)d_ws; (void)ws_size;
  const float* q  = (const float*)d_in[0];
  const float* kv = (const float*)d_in[1];
  float* out = (float*)d_out;
  dim3 grid(B_ * NH_ * (SQ_ / 64));  // 1024 blocks, 4 waves each
  fa_fwd<<<grid, 256, 0, stream>>>(q, kv, out);
}

// Round 4
// 119.304 us; speedup vs baseline: 1.1218x; 1.1218x over previous
//
#include <hip/hip_runtime.h>
#include <hip/hip_bf16.h>

#define B_    2
#define SQ_   2048
#define SK_   2048
#define NH_   16
#define DH_   64
#define WIN_  256
#define NEG_  -30000.0f

typedef __bf16 bf16_t;
typedef bf16_t bf16x8 __attribute__((ext_vector_type(8)));
typedef bf16_t bf16x4 __attribute__((ext_vector_type(4)));
typedef float  f32x4  __attribute__((ext_vector_type(4)));

// 64-element rows + 8 pad = 144 B stride: keeps every b128/b64 access 16B-aligned,
// 2-way bank alias only (free per m136)
#define KSTRIDE 72
#define VSTRIDE 72
#define PSTRIDE 72

__global__ __launch_bounds__(256, 2)
void fa_fwd(const float* __restrict__ qg, const float* __restrict__ kvg,
            float* __restrict__ outg) {
  const int tid  = threadIdx.x;
  const int wid  = tid >> 6;
  const int lane = tid & 63;
  const int quad = lane >> 4;
  const int li   = lane & 15;

  const int bid = blockIdx.x;
  const int qb  = bid >> 5;   // 16 q-blocks of 128 rows
  const int bh  = bid & 31;   // same bh -> same bid%8 -> same XCD (L2 kv locality)
  const int b   = bh >> 4;
  const int h   = bh & 15;

  const int q0b = qb * 128;
  const int q0  = q0b + wid * 32;   // this wave: 32 q-rows as 2 tiles of 16

  __shared__ __align__(16) bf16_t sK [64 * KSTRIDE];      // K tile [key][d]
  __shared__ __align__(16) bf16_t sVT[64 * VSTRIDE];      // V transposed [d][key]
  __shared__ __align__(16) bf16_t sP [4 * 32 * PSTRIDE];  // per-wave P [qrow][key]
  bf16_t* pl = sP + wid * 32 * PSTRIDE;

  // ---- Q fragments for both row-tiles, scale * log2(e) folded ----
  const float qscale = 0.125f * 1.44269504088896340736f;
  bf16x8 qfrag[2][2];
#pragma unroll
  for (int qt = 0; qt < 2; ++qt) {
    const float* qrow = qg + ((size_t)((b * SQ_ + q0 + qt * 16 + li) * NH_ + h)) * DH_;
#pragma unroll
    for (int c = 0; c < 2; ++c) {
      f32x4 a0 = *(const f32x4*)(qrow + c * 32 + quad * 8);
      f32x4 a1 = *(const f32x4*)(qrow + c * 32 + quad * 8 + 4);
#pragma unroll
      for (int i = 0; i < 4; ++i) {
        qfrag[qt][c][i]     = (bf16_t)(a0[i] * qscale);
        qfrag[qt][c][i + 4] = (bf16_t)(a1[i] * qscale);
      }
    }
  }

  f32x4 oacc[2][4];
#pragma unroll
  for (int qt = 0; qt < 2; ++qt)
#pragma unroll
    for (int t = 0; t < 4; ++t) { f32x4 z = {0.f, 0.f, 0.f, 0.f}; oacc[qt][t] = z; }
  float m[2] = {NEG_, NEG_}, l[2] = {0.f, 0.f};

  // block-uniform key range; q0b multiple of 128 so bounds are 64-aligned already
  int klo = q0b - WIN_; if (klo < 0) klo = 0;
  int khi = q0b + 127 + WIN_ + 1; if (khi > SK_) khi = SK_;

  const float* kbase = kvg + (size_t)b * SK_ * 2 * NH_ * DH_ + (size_t)h * DH_;
  const float* vbase = kbase + NH_ * DH_;
  const size_t krow_stride = 2 * NH_ * DH_;

  // staging: 256 threads cover 64 keys x 64 d (16 floats each of K and V)
  const int skey = tid >> 2;        // 0..63
  const int sd0  = (tid & 3) * 16;  // 0,16,32,48

  // ---- prefetch tile 0 into registers ----
  f32x4 ka[4], va[4];
  {
    const float* kr = kbase + (size_t)(klo + skey) * krow_stride + sd0;
    const float* vr = vbase + (size_t)(klo + skey) * krow_stride + sd0;
#pragma unroll
    for (int i = 0; i < 4; ++i) { ka[i] = *(const f32x4*)(kr + 4 * i); va[i] = *(const f32x4*)(vr + 4 * i); }
  }

  for (int kk = klo; kk < khi; kk += 64) {
    // ---- write prefetched registers to LDS ----
    {
      bf16x8 w0, w1;
#pragma unroll
      for (int i = 0; i < 4; ++i) {
        w0[i] = (bf16_t)ka[0][i]; w0[i + 4] = (bf16_t)ka[1][i];
        w1[i] = (bf16_t)ka[2][i]; w1[i + 4] = (bf16_t)ka[3][i];
      }
      *(bf16x8*)(sK + skey * KSTRIDE + sd0)     = w0;
      *(bf16x8*)(sK + skey * KSTRIDE + sd0 + 8) = w1;
#pragma unroll
      for (int i = 0; i < 4; ++i)
#pragma unroll
        for (int j = 0; j < 4; ++j)
          sVT[(sd0 + 4 * i + j) * VSTRIDE + skey] = (bf16_t)va[i][j];
    }
    __syncthreads();

    // ---- issue next tile's global loads (in flight across the compute) ----
    if (kk + 64 < khi) {
      const float* kr = kbase + (size_t)(kk + 64 + skey) * krow_stride + sd0;
      const float* vr = vbase + (size_t)(kk + 64 + skey) * krow_stride + sd0;
#pragma unroll
      for (int i = 0; i < 4; ++i) { ka[i] = *(const f32x4*)(kr + 4 * i); va[i] = *(const f32x4*)(vr + 4 * i); }
    }

    // ---- S^T = K . Q^T : 4 key subtiles x 2 q-tiles, D=64 as two K=32 chunks ----
    f32x4 sc[2][4];
#pragma unroll
    for (int s = 0; s < 4; ++s) {
      bf16x8 kf0 = *(const bf16x8*)(sK + (s * 16 + li) * KSTRIDE + quad * 8);
      bf16x8 kf1 = *(const bf16x8*)(sK + (s * 16 + li) * KSTRIDE + 32 + quad * 8);
#pragma unroll
      for (int qt = 0; qt < 2; ++qt) {
        f32x4 acc = {0.f, 0.f, 0.f, 0.f};
        acc = __builtin_amdgcn_mfma_f32_16x16x32_bf16(kf0, qfrag[qt][0], acc, 0, 0, 0);
        acc = __builtin_amdgcn_mfma_f32_16x16x32_bf16(kf1, qfrag[qt][1], acc, 0, 0, 0);
        sc[qt][s] = acc;
      }
    }

    // ---- mask + online softmax + P write, per q-tile ----
    float alpha[2];
#pragma unroll
    for (int qt = 0; qt < 2; ++qt) {
      const int qa = q0 + qt * 16 + li;
#pragma unroll
      for (int s = 0; s < 4; ++s)
#pragma unroll
        for (int r = 0; r < 4; ++r) {
          int key = kk + s * 16 + quad * 4 + r;
          unsigned dd = (unsigned)(key - qa + WIN_);
          if (dd > 2u * WIN_) sc[qt][s][r] = NEG_;
        }
      float tmax = NEG_;
#pragma unroll
      for (int s = 0; s < 4; ++s)
        tmax = fmaxf(tmax, fmaxf(fmaxf(sc[qt][s][0], sc[qt][s][1]),
                                 fmaxf(sc[qt][s][2], sc[qt][s][3])));
      tmax = fmaxf(tmax, __shfl_xor(tmax, 16));
      tmax = fmaxf(tmax, __shfl_xor(tmax, 32));
      float mnew = fmaxf(m[qt], tmax);
      alpha[qt] = exp2f(m[qt] - mnew);
      float psum = 0.f;
#pragma unroll
      for (int s = 0; s < 4; ++s) {
        bf16x4 pk;
#pragma unroll
        for (int r = 0; r < 4; ++r) {
          float p = exp2f(sc[qt][s][r] - mnew);
          psum += p;
          pk[r] = (bf16_t)p;
        }
        *(bf16x4*)(pl + (qt * 16 + li) * PSTRIDE + s * 16 + quad * 4) = pk;
      }
      psum += __shfl_xor(psum, 16);
      psum += __shfl_xor(psum, 32);
      l[qt] = l[qt] * alpha[qt] + psum;
      m[qt] = mnew;
    }

    // wave-local drain: P round-trip is per-wave, no block barrier needed
    asm volatile("s_waitcnt lgkmcnt(0)" ::: "memory");

    // ---- rescale O accumulators ----
#pragma unroll
    for (int qt = 0; qt < 2; ++qt) {
      float al[4];
#pragma unroll
      for (int r = 0; r < 4; ++r) al[r] = __shfl(alpha[qt], quad * 4 + r);
#pragma unroll
      for (int t = 0; t < 4; ++t) {
        oacc[qt][t][0] *= al[0]; oacc[qt][t][1] *= al[1];
        oacc[qt][t][2] *= al[2]; oacc[qt][t][3] *= al[3];
      }
    }

    // ---- O += P . V : K=64 as two 32-chunks; vf shared across q-tiles ----
#pragma unroll
    for (int kc = 0; kc < 2; ++kc) {
      bf16x8 pf0 = *(const bf16x8*)(pl + li * PSTRIDE + kc * 32 + quad * 8);
      bf16x8 pf1 = *(const bf16x8*)(pl + (16 + li) * PSTRIDE + kc * 32 + quad * 8);
#pragma unroll
      for (int t = 0; t < 4; ++t) {
        bf16x8 vf = *(const bf16x8*)(sVT + (16 * t + li) * VSTRIDE + kc * 32 + quad * 8);
        oacc[0][t] = __builtin_amdgcn_mfma_f32_16x16x32_bf16(pf0, vf, oacc[0][t], 0, 0, 0);
        oacc[1][t] = __builtin_amdgcn_mfma_f32_16x16x32_bf16(pf1, vf, oacc[1][t], 0, 0, 0);
      }
    }
    __syncthreads();
  }

  // ---- epilogue ----
#pragma unroll
  for (int qt = 0; qt < 2; ++qt) {
    float rl[4];
#pragma unroll
    for (int r = 0; r < 4; ++r) {
      float lv = __shfl(l[qt], quad * 4 + r);
      rl[r] = 1.0f / lv;
    }
    float* orow = outg + ((size_t)((b * SQ_ + q0 + qt * 16) * NH_ + h)) * DH_;
#pragma unroll
    for (int t = 0; t < 4; ++t)
#pragma unroll
      for (int r = 0; r < 4; ++r)
        orow[(size_t)(quad * 4 + r) * (NH_ * DH_) + 16 * t + li] = oacc[qt][t][r] * rl[r];
  }
}

extern "C" void kernel_launch(void* const* d_in, const int* in_sizes, int n_in,
                              void* d_out, int out_size, void* d_ws, size_t ws_size,
                              hipStream_t stream) {
  (void)in_sizes; (void)n_in; (void)out_size; (void)d_ws; (void)ws_size;
  const float* q  = (const float*)d_in[0];
  const float* kv = (const float*)d_in[1];
  float* out = (float*)d_out;
  dim3 grid(B_ * NH_ * (SQ_ / 128));  // 512 blocks, 4 waves each, all co-resident
  fa_fwd<<<grid, 256, 0, stream>>>(q, kv, out);
}

// Round 5
// 111.897 us; speedup vs baseline: 1.1960x; 1.0662x over previous
//
#include <hip/hip_runtime.h>
#include <hip/hip_bf16.h>

#define B_    2
#define SQ_   2048
#define SK_   2048
#define NH_   16
#define DH_   64
#define WIN_  256
#define NEG_  -30000.0f

typedef __bf16 bf16_t;
typedef bf16_t bf16x8 __attribute__((ext_vector_type(8)));
typedef bf16_t bf16x4 __attribute__((ext_vector_type(4)));
typedef float  f32x4  __attribute__((ext_vector_type(4)));

// 64-element rows + 8 pad = 144 B stride: b128/b64 accesses stay 16B-aligned
#define KSTRIDE 72
#define VSTRIDE 72
#define PSTRIDE 72

__global__ __launch_bounds__(512, 4)
void fa_fwd(const float* __restrict__ qg, const float* __restrict__ kvg,
            float* __restrict__ outg) {
  const int tid  = threadIdx.x;
  const int wid  = tid >> 6;      // 0..7, each wave owns 16 q-rows
  const int lane = tid & 63;
  const int quad = lane >> 4;
  const int li   = lane & 15;

  const int bid = blockIdx.x;
  const int qb  = bid >> 5;   // 16 q-blocks of 128 rows
  const int bh  = bid & 31;   // same bh -> same XCD (kv L2 locality)
  const int b   = bh >> 4;
  const int h   = bh & 15;

  const int q0b = qb * 128;
  const int q0  = q0b + wid * 16;

  __shared__ __align__(16) bf16_t sK [2][64 * KSTRIDE];   // K tiles [key][d]
  __shared__ __align__(16) bf16_t sVT[2][64 * VSTRIDE];   // V^T tiles [d][key^swz]
  __shared__ __align__(16) bf16_t sP [8][16 * PSTRIDE];   // per-wave P [qrow][key]
  bf16_t* pl = sP[wid];

  // ---- Q fragments (16 rows), scale * log2(e) folded ----
  const float qscale = 0.125f * 1.44269504088896340736f;
  const float* qrow = qg + ((size_t)((b * SQ_ + q0 + li) * NH_ + h)) * DH_;
  bf16x8 qfrag[2];
#pragma unroll
  for (int c = 0; c < 2; ++c) {
    f32x4 a0 = *(const f32x4*)(qrow + c * 32 + quad * 8);
    f32x4 a1 = *(const f32x4*)(qrow + c * 32 + quad * 8 + 4);
#pragma unroll
    for (int i = 0; i < 4; ++i) {
      qfrag[c][i]     = (bf16_t)(a0[i] * qscale);
      qfrag[c][i + 4] = (bf16_t)(a1[i] * qscale);
    }
  }

  f32x4 oacc[4];
#pragma unroll
  for (int t = 0; t < 4; ++t) { f32x4 z = {0.f, 0.f, 0.f, 0.f}; oacc[t] = z; }
  float m = NEG_, l = 0.f;

  // block-uniform 64-aligned key range
  int klo = q0b - WIN_; if (klo < 0) klo = 0;
  int khi = q0b + 127 + WIN_ + 1; if (khi > SK_) khi = SK_;

  const float* kbase = kvg + (size_t)b * SK_ * 2 * NH_ * DH_ + (size_t)h * DH_;
  const float* vbase = kbase + NH_ * DH_;
  const size_t krow_stride = 2 * NH_ * DH_;

  // staging: 512 threads cover 64 keys x 64 d (8 floats each of K and V)
  const int skey = tid >> 3;        // 0..63
  const int sd0  = (tid & 7) * 8;   // 0,8,...,56
  // swizzled V^T column: spreads the transpose scatter across all 32 banks
  const int vcol = skey ^ (((sd0 >> 3) & 7) << 3);

  f32x4 ka[2], va[2];
  // ---- prologue: load + stage tile 0 into buf 0 ----
  {
    const float* kr = kbase + (size_t)(klo + skey) * krow_stride + sd0;
    const float* vr = vbase + (size_t)(klo + skey) * krow_stride + sd0;
    ka[0] = *(const f32x4*)kr;       ka[1] = *(const f32x4*)(kr + 4);
    va[0] = *(const f32x4*)vr;       va[1] = *(const f32x4*)(vr + 4);
  }
  {
    bf16x8 w;
#pragma unroll
    for (int i = 0; i < 4; ++i) { w[i] = (bf16_t)ka[0][i]; w[i + 4] = (bf16_t)ka[1][i]; }
    *(bf16x8*)(&sK[0][skey * KSTRIDE + sd0]) = w;
#pragma unroll
    for (int i = 0; i < 4; ++i) {
      sVT[0][(sd0 + i)     * VSTRIDE + vcol] = (bf16_t)va[0][i];
      sVT[0][(sd0 + 4 + i) * VSTRIDE + vcol] = (bf16_t)va[1][i];
    }
  }
  __syncthreads();

  int buf = 0;
  for (int kk = klo; kk < khi; kk += 64) {
    const bool nxt = (kk + 64 < khi);   // block-uniform
    // ---- issue next tile's global loads (in flight across compute) ----
    if (nxt) {
      const float* kr = kbase + (size_t)(kk + 64 + skey) * krow_stride + sd0;
      const float* vr = vbase + (size_t)(kk + 64 + skey) * krow_stride + sd0;
      ka[0] = *(const f32x4*)kr;       ka[1] = *(const f32x4*)(kr + 4);
      va[0] = *(const f32x4*)vr;       va[1] = *(const f32x4*)(vr + 4);
    }

    // ---- compute only if this tile intersects the wave's window ----
    if (kk + 63 >= q0 - WIN_ && kk <= q0 + 15 + WIN_) {
      // S^T = K . Q^T : 4 key subtiles, D=64 as two K=32 chunks
      f32x4 sc[4];
#pragma unroll
      for (int s = 0; s < 4; ++s) {
        bf16x8 kf0 = *(const bf16x8*)(&sK[buf][(s * 16 + li) * KSTRIDE + quad * 8]);
        bf16x8 kf1 = *(const bf16x8*)(&sK[buf][(s * 16 + li) * KSTRIDE + 32 + quad * 8]);
        f32x4 acc = {0.f, 0.f, 0.f, 0.f};
        acc = __builtin_amdgcn_mfma_f32_16x16x32_bf16(kf0, qfrag[0], acc, 0, 0, 0);
        acc = __builtin_amdgcn_mfma_f32_16x16x32_bf16(kf1, qfrag[1], acc, 0, 0, 0);
        sc[s] = acc;
      }
      // window mask only on boundary tiles (wave-uniform branch)
      if (kk < q0 - 241 || kk > q0 + 193) {
        const int qa = q0 + li;
#pragma unroll
        for (int s = 0; s < 4; ++s)
#pragma unroll
          for (int r = 0; r < 4; ++r) {
            int key = kk + s * 16 + quad * 4 + r;
            unsigned dd = (unsigned)(key - qa + WIN_);
            if (dd > 2u * WIN_) sc[s][r] = NEG_;
          }
      }
      // online softmax, state per q-col = li
      float tmax = NEG_;
#pragma unroll
      for (int s = 0; s < 4; ++s)
        tmax = fmaxf(tmax, fmaxf(fmaxf(sc[s][0], sc[s][1]), fmaxf(sc[s][2], sc[s][3])));
      tmax = fmaxf(tmax, __shfl_xor(tmax, 16));
      tmax = fmaxf(tmax, __shfl_xor(tmax, 32));
      float mnew  = fmaxf(m, tmax);
      float alpha = exp2f(m - mnew);
      float psum = 0.f;
#pragma unroll
      for (int s = 0; s < 4; ++s) {
        bf16x4 pk;
#pragma unroll
        for (int r = 0; r < 4; ++r) {
          float p = exp2f(sc[s][r] - mnew);
          psum += p;
          pk[r] = (bf16_t)p;
        }
        *(bf16x4*)(&pl[li * PSTRIDE + s * 16 + quad * 4]) = pk;
      }
      psum += __shfl_xor(psum, 16);
      psum += __shfl_xor(psum, 32);
      l = l * alpha + psum;
      m = mnew;

      // wave-local drain: sP round-trip is per-wave
      asm volatile("s_waitcnt lgkmcnt(0)" ::: "memory");

      // rescale O
      float al[4];
#pragma unroll
      for (int r = 0; r < 4; ++r) al[r] = __shfl(alpha, quad * 4 + r);
#pragma unroll
      for (int t = 0; t < 4; ++t) {
        oacc[t][0] *= al[0]; oacc[t][1] *= al[1];
        oacc[t][2] *= al[2]; oacc[t][3] *= al[3];
      }
      // O += P . V
#pragma unroll
      for (int kc = 0; kc < 2; ++kc) {
        bf16x8 pf = *(const bf16x8*)(&pl[li * PSTRIDE + kc * 32 + quad * 8]);
#pragma unroll
        for (int t = 0; t < 4; ++t) {
          const int d = 16 * t + li;
          const int c = ((2 * t + (li >> 3)) & 7) << 3;
          bf16x8 vf = *(const bf16x8*)(&sVT[buf][d * VSTRIDE + ((kc * 32 + quad * 8) ^ c)]);
          oacc[t] = __builtin_amdgcn_mfma_f32_16x16x32_bf16(pf, vf, oacc[t], 0, 0, 0);
        }
      }
    }

    // ---- stage next tile into the other buffer (prev reads fenced last iter) ----
    if (nxt) {
      bf16x8 w;
#pragma unroll
      for (int i = 0; i < 4; ++i) { w[i] = (bf16_t)ka[0][i]; w[i + 4] = (bf16_t)ka[1][i]; }
      *(bf16x8*)(&sK[buf ^ 1][skey * KSTRIDE + sd0]) = w;
#pragma unroll
      for (int i = 0; i < 4; ++i) {
        sVT[buf ^ 1][(sd0 + i)     * VSTRIDE + vcol] = (bf16_t)va[0][i];
        sVT[buf ^ 1][(sd0 + 4 + i) * VSTRIDE + vcol] = (bf16_t)va[1][i];
      }
    }
    __syncthreads();   // the single barrier per iteration
    buf ^= 1;
  }

  // ---- epilogue ----
  float rl[4];
#pragma unroll
  for (int r = 0; r < 4; ++r) {
    float lv = __shfl(l, quad * 4 + r);
    rl[r] = 1.0f / lv;
  }
  float* orow = outg + ((size_t)((b * SQ_ + q0) * NH_ + h)) * DH_;
#pragma unroll
  for (int t = 0; t < 4; ++t)
#pragma unroll
    for (int r = 0; r < 4; ++r)
      orow[(size_t)(quad * 4 + r) * (NH_ * DH_) + 16 * t + li] = oacc[t][r] * rl[r];
}

extern "C" void kernel_launch(void* const* d_in, const int* in_sizes, int n_in,
                              void* d_out, int out_size, void* d_ws, size_t ws_size,
                              hipStream_t stream) {
  (void)in_sizes; (void)n_in; (void)out_size; (void)d_ws; (void)ws_size;
  const float* q  = (const float*)d_in[0];
  const float* kv = (const float*)d_in[1];
  float* out = (float*)d_out;
  dim3 grid(B_ * NH_ * (SQ_ / 128));  // 512 blocks x 8 waves = 16 waves/CU
  fa_fwd<<<grid, 512, 0, stream>>>(q, kv, out);
}